// Round 5
// baseline (146.147 us; speedup 1.0000x reference)
//
#include <hip/hip_runtime.h>

#define BLOCK 256
#define QPT 2          // queries per thread (2 -> 2048 blocks -> 8 waves/SIMD)
#define TILE 512       // max train points staged per iteration
#define TILE2 (TILE / 2)
#define MAX_SEGS 64
#define RSPLIT 4       // seg-parallelism per query in the reduce

typedef float v2f __attribute__((ext_vector_type(2)));

// scores = -0.5*((q-x)*w)^2 ; fold sqrt(0.5*log2(e)) into w so exp2 applies
// directly: exp2(-(t*t)) with t = fma(q, a, nb), a = w*K, nb = -x*w*K.
#define KFOLD 0.8493218f  // sqrt(0.5 * log2(e))

// R4 model (exact fit): 96.6 cy/j2 = 32 cy scalar-VALU + 4 exp x 16 cy trans,
// trans SERIALIZES with VALU issue -> v_exp is 2/3 of the kernel. Replace it
// with packed-VALU poly exp2 in asm (clang won't form v_pk_*_f32 from C):
//   u = t^2; n = rndne(u); g = u-n in [-.5,.5]
//   e = 2^-n * P(g),  P = deg-5 economized poly for exp2(-g) (rel err ~2e-7)
//   2^-n bits = ((-n)<<23) + 0x3F800000 via v_cvt_i32_f32(-n) + v_lshl_add
// 11 pk + 6 scalar per i -> ~74 cy/j2 vs 96. Explicit clobbers v48-v55 give
// element access + aligned pairs; WAW serialization across blocks is free at
// 8 waves/SIMD (issue-port-bound). Valid for u in [0,126]; data gives u<=~52,
// pad uses nb=11 (u=121 -> e~2^-121~0).
__global__ __launch_bounds__(BLOCK, 8) void nw_partial(
    const float* __restrict__ q, const float* __restrict__ xt,
    const float* __restrict__ yt, const float* __restrict__ w,
    float2* __restrict__ partial, int n_q, int n_t, int segs)
{
    __shared__ float4 tileA[TILE2];   // {a_j, a_j+1, nb_j, nb_j+1}
    __shared__ float2 tileY[TILE2];   // {y_j, y_j+1}

    const int seg = blockIdx.x;
    const int tid = threadIdx.x;
    const int qbase = blockIdx.y * (BLOCK * QPT) + tid;

    // P(g) ~ exp2(-g) on [-0.5,0.5]: Taylor-6 with g^6 Chebyshev-economized.
    const v2f NEG1 = {-1.0f, -1.0f};
    const v2f K5 = {-1.3334021e-3f, -1.3334021e-3f};
    const v2f K4 = { 9.6758931e-3f,  9.6758931e-3f};
    const v2f K3 = {-5.5504109e-2f, -5.5504109e-2f};
    const v2f K2 = { 2.4022110e-1f,  2.4022110e-1f};
    const v2f K1 = {-6.9314718e-1f, -6.9314718e-1f};
    const v2f K0 = { 1.0000001f,     1.0000001f};
    const int EXPBIAS = 0x3F800000;   // 127<<23

    v2f q2[QPT];       // {q_i, q_i} splat, loop-invariant
    v2f num2[QPT], den2[QPT];
#pragma unroll
    for (int i = 0; i < QPT; ++i) {
        int qi = qbase + i * BLOCK;
        float qv = (qi < n_q) ? q[qi] : 0.f;
        q2[i] = (v2f){qv, qv};
        num2[i] = (v2f){0.f, 0.f};
        den2[i] = (v2f){0.f, 0.f};
    }

    const int seg_len = (n_t + segs - 1) / segs;
    const int s0 = seg * seg_len;
    const int s1 = min(s0 + seg_len, n_t);

    float* tA = (float*)tileA;
    float* tY = (float*)tileY;

    for (int base = s0; base < s1; base += TILE) {
        const int cnt = min(TILE, s1 - base);
        const int cnt2 = (cnt + 1) >> 1;
        __syncthreads();
        for (int l = tid; l < cnt; l += BLOCK) {
            int jj = base + l;
            float a = w[jj] * KFOLD;
            float nb = -xt[jj] * a;
            int p = l >> 1, h = l & 1;
            tA[p * 4 + h] = a;
            tA[p * 4 + 2 + h] = nb;
            tY[p * 2 + h] = yt[jj];
        }
        if (tid == 0 && (cnt & 1)) {   // pad odd tail: u=121 -> e ~ 2^-121 ~ 0
            int p = cnt >> 1;
            tA[p * 4 + 1] = 0.f;
            tA[p * 4 + 3] = 11.0f;
            tY[p * 2 + 1] = 0.f;
        }
        __syncthreads();
#pragma unroll 8
        for (int j2 = 0; j2 < cnt2; ++j2) {
            float4 A = tileA[j2];
            float2 Y = tileY[j2];
            v2f a2 = (v2f){A.x, A.y};
            v2f nb2 = (v2f){A.z, A.w};
            v2f y2 = (v2f){Y.x, Y.y};
#pragma unroll
            for (int i = 0; i < QPT; ++i) {
                asm("v_pk_fma_f32 v[48:49], %2, %3, %4\n\t"            // t = q*a+nb
                    "v_pk_mul_f32 v[48:49], v[48:49], v[48:49]\n\t"    // u = t*t
                    "v_rndne_f32 v50, v48\n\t"                         // n0
                    "v_rndne_f32 v51, v49\n\t"                         // n1
                    "v_pk_fma_f32 v[52:53], v[50:51], %5, v[48:49]\n\t" // g = u-n
                    "v_cvt_i32_f32 v54, -v50\n\t"                      // -n0 (int)
                    "v_cvt_i32_f32 v55, -v51\n\t"
                    "v_lshl_add_u32 v54, v54, 23, %12\n\t"             // bits(2^-n0)
                    "v_lshl_add_u32 v55, v55, 23, %12\n\t"
                    "v_pk_fma_f32 v[48:49], %6, v[52:53], %7\n\t"      // K5*g+K4
                    "v_pk_fma_f32 v[48:49], v[48:49], v[52:53], %8\n\t"
                    "v_pk_fma_f32 v[48:49], v[48:49], v[52:53], %9\n\t"
                    "v_pk_fma_f32 v[48:49], v[48:49], v[52:53], %10\n\t"
                    "v_pk_fma_f32 v[48:49], v[48:49], v[52:53], %11\n\t" // P(g)
                    "v_pk_mul_f32 v[52:53], v[48:49], v[54:55]\n\t"    // e = P*2^-n
                    "v_pk_fma_f32 %0, v[52:53], %13, %0\n\t"           // num += e*y
                    "v_pk_add_f32 %1, %1, v[52:53]"                    // den += e
                    : "+v"(num2[i]), "+v"(den2[i])
                    : "v"(q2[i]), "v"(a2), "v"(nb2), "v"(NEG1),
                      "v"(K5), "v"(K4), "v"(K3), "v"(K2), "v"(K1), "v"(K0),
                      "s"(EXPBIAS), "v"(y2)
                    : "v48","v49","v50","v51","v52","v53","v54","v55");
            }
        }
    }

#pragma unroll
    for (int i = 0; i < QPT; ++i) {
        int qi = qbase + i * BLOCK;
        if (qi < n_q)
            partial[seg * n_q + qi] =
                make_float2(num2[i].x + num2[i].y, den2[i].x + den2[i].y);
    }
}

// Block handles 64 queries; RSPLIT waves split the segs dimension so each
// wave's 64 lanes read 64 consecutive qi -> fully coalesced.
__global__ __launch_bounds__(BLOCK) void nw_reduce(
    const float2* __restrict__ partial, float* __restrict__ out,
    int n_q, int segs)
{
    __shared__ float2 red[RSPLIT][64];
    const int tid = threadIdx.x;
    const int c = tid >> 6;          // 0..3 (seg chunk = wave index)
    const int ql = tid & 63;         // query within block
    const int qi = blockIdx.x * 64 + ql;

    float num = 0.f, den = 0.f;
    if (qi < n_q) {
        for (int s = c; s < segs; s += RSPLIT) {
            float2 p = partial[(size_t)s * n_q + qi];
            num += p.x;
            den += p.y;
        }
    }
    red[c][ql] = make_float2(num, den);
    __syncthreads();
    if (c == 0 && qi < n_q) {
        float2 r1 = red[1][ql], r2 = red[2][ql], r3 = red[3][ql];
        num += r1.x + r2.x + r3.x;
        den += r1.y + r2.y + r3.y;
        out[qi] = num / den;
    }
}

extern "C" void kernel_launch(void* const* d_in, const int* in_sizes, int n_in,
                              void* d_out, int out_size, void* d_ws, size_t ws_size,
                              hipStream_t stream) {
    const float* q  = (const float*)d_in[0];
    const float* xt = (const float*)d_in[1];
    const float* yt = (const float*)d_in[2];
    const float* w  = (const float*)d_in[3];
    const int n_q = in_sizes[0];
    const int n_t = in_sizes[1];

    // split-K segments, clamped so partials fit in the workspace
    int segs = MAX_SEGS;
    size_t need = (size_t)segs * (size_t)n_q * sizeof(float2);
    if (need > ws_size) {
        segs = (int)(ws_size / ((size_t)n_q * sizeof(float2)));
        if (segs < 1) segs = 1;
    }

    float2* partial = (float2*)d_ws;
    dim3 grid(segs, (n_q + BLOCK * QPT - 1) / (BLOCK * QPT));
    nw_partial<<<grid, BLOCK, 0, stream>>>(q, xt, yt, w, partial, n_q, n_t, segs);
    nw_reduce<<<(n_q + 63) / 64, BLOCK, 0, stream>>>(partial, (float*)d_out,
                                                     n_q, segs);
}